// Round 1
// baseline (81.605 us; speedup 1.0000x reference)
//
#include <hip/hip_runtime.h>
#include <hip/hip_bf16.h>
#include <stdint.h>

#define BB 32
#define NN 1024
#define MM 1024
#define DD 256

#define BM 128
#define BN 128
#define BK 64

typedef __attribute__((ext_vector_type(8))) short short8;
typedef __attribute__((ext_vector_type(4))) float floatx4;

__device__ inline unsigned short f2bf(float x) {
    __hip_bfloat16 h = __float2bfloat16(x);
    union { __hip_bfloat16 h; unsigned short u; } cv;
    cv.h = h;
    return cv.u;
}

// ---------------------------------------------------------------------------
// Init: set rowmin/colmin (contiguous 2*BB*1024 uints) to +inf bits
// ---------------------------------------------------------------------------
__global__ __launch_bounds__(256) void init_minbuf(unsigned int* __restrict__ p) {
    p[blockIdx.x * 256 + threadIdx.x] = 0x7F800000u; // +inf
}

// ---------------------------------------------------------------------------
// Convert fp32 -> bf16 (workspace) + per-row sum of squares (fp32 exact).
// One wave per row of 256 floats: lane loads float4 (16B), 64*4 = 256.
// ---------------------------------------------------------------------------
__global__ __launch_bounds__(256) void convert_kernel(
        const float* __restrict__ h1, const float* __restrict__ h2,
        __hip_bfloat16* __restrict__ h1b, __hip_bfloat16* __restrict__ h2b,
        float* __restrict__ sq1, float* __restrict__ sq2) {
    int wave = blockIdx.x * 4 + (threadIdx.x >> 6);
    int lane = threadIdx.x & 63;
    const int total1 = BB * NN;

    const float* src;
    __hip_bfloat16* dst;
    float* sq;
    int row;
    if (wave < total1) { src = h1; dst = h1b; sq = sq1; row = wave; }
    else               { src = h2; dst = h2b; sq = sq2; row = wave - total1; }

    const float4* p = (const float4*)(src + (size_t)row * DD);
    float4 v = p[lane];

    float s = v.x * v.x + v.y * v.y + v.z * v.z + v.w * v.w;
    #pragma unroll
    for (int off = 32; off; off >>= 1) s += __shfl_xor(s, off, 64);

    ushort4 o;
    o.x = f2bf(v.x); o.y = f2bf(v.y); o.z = f2bf(v.z); o.w = f2bf(v.w);
    *(ushort4*)((unsigned short*)(dst + (size_t)row * DD) + lane * 4) = o;

    if (lane == 0) sq[row] = s;
}

// ---------------------------------------------------------------------------
// Batched GEMM + fused Hausdorff epilogue.
// Grid: (64 tiles, 32 batches). Block: 256 threads = 4 waves (2x2 of 64x64).
// dist[n][m] = sq1[n] + sq2[m] - 2 * <h1[n], h2[m]>, clamped >= 0.
// Row mins (over m) -> atomicMin rowmin[b][n]; col mins (over n) -> colmin[b][m].
// ---------------------------------------------------------------------------
__global__ __launch_bounds__(256) void gemm_kernel(
        const __hip_bfloat16* __restrict__ h1b, const __hip_bfloat16* __restrict__ h2b,
        const float* __restrict__ sq1, const float* __restrict__ sq2,
        unsigned int* __restrict__ rowmin, unsigned int* __restrict__ colmin) {
    __shared__ __align__(16) __hip_bfloat16 As[BM][BK];
    __shared__ __align__(16) __hip_bfloat16 Bs[BN][BK];

    const int b    = blockIdx.y;
    const int tile = blockIdx.x;       // 0..63
    const int tn   = tile >> 3;
    const int tm   = tile & 7;
    const int n0   = tn * BM;
    const int m0   = tm * BN;

    const int tid  = threadIdx.x;
    const int wave = tid >> 6;
    const int lane = tid & 63;
    const int wn   = (wave >> 1) * 64; // wave subtile origin (n)
    const int wm   = (wave & 1) * 64;  // wave subtile origin (m)

    const __hip_bfloat16* Ag = h1b + ((size_t)b * NN + n0) * DD;
    const __hip_bfloat16* Bg = h2b + ((size_t)b * MM + m0) * DD;

    floatx4 acc[4][4] = {};

    const int krow = lane >> 4;  // 0..3  (k-chunk group of 8)
    const int rrow = lane & 15;  // row/col within 16x16 fragment

    for (int ks = 0; ks < DD / BK; ++ks) {
        // stage: 128x64 bf16 each for A and B; thread t moves 8 bf16/issue
        #pragma unroll
        for (int it = 0; it < 4; ++it) {
            int e = (it * 256 + tid) * 8;  // flat elem index in [0, 8192)
            int r = e >> 6;                // /BK
            int c = e & 63;                // %BK
            *(short8*)&As[r][c] = *(const short8*)(Ag + (size_t)r * DD + ks * BK + c);
            *(short8*)&Bs[r][c] = *(const short8*)(Bg + (size_t)r * DD + ks * BK + c);
        }
        __syncthreads();

        #pragma unroll
        for (int kk = 0; kk < 2; ++kk) {
            short8 af[4], bfr[4];
            #pragma unroll
            for (int i = 0; i < 4; ++i)
                af[i] = *(const short8*)&As[wn + i * 16 + rrow][kk * 32 + krow * 8];
            #pragma unroll
            for (int j = 0; j < 4; ++j)
                bfr[j] = *(const short8*)&Bs[wm + j * 16 + rrow][kk * 32 + krow * 8];
            #pragma unroll
            for (int i = 0; i < 4; ++i)
                #pragma unroll
                for (int j = 0; j < 4; ++j)
                    acc[i][j] = __builtin_amdgcn_mfma_f32_16x16x32_bf16(
                        af[i], bfr[j], acc[i][j], 0, 0, 0);
        }
        __syncthreads();
    }

    // ---- epilogue ----
    // D mapping (16x16x32 bf16): col = lane&15, row = (lane>>4)*4 + reg
    const float* s1 = sq1 + b * NN + n0 + wn;
    const float* s2 = sq2 + b * MM + m0 + wm;
    unsigned int* rm = rowmin + b * NN + n0;
    unsigned int* cm = colmin + b * MM + m0;

    const int lrow = (lane >> 4) * 4;
    const int lcol = lane & 15;

    float s2v[4];
    #pragma unroll
    for (int j = 0; j < 4; ++j) s2v[j] = s2[j * 16 + lcol];

    float cmin[4] = {3.0e38f, 3.0e38f, 3.0e38f, 3.0e38f};

    #pragma unroll
    for (int i = 0; i < 4; ++i) {
        #pragma unroll
        for (int r = 0; r < 4; ++r) {
            float s1v = s1[i * 16 + lrow + r];
            float pm = 3.0e38f;
            #pragma unroll
            for (int j = 0; j < 4; ++j) {
                float dist = s1v + s2v[j] - 2.0f * acc[i][j][r];
                dist = fmaxf(dist, 0.0f);
                pm = fminf(pm, dist);
                cmin[j] = fminf(cmin[j], dist);
            }
            // reduce over the 16 lanes sharing this n (lane bits 0..3 vary m)
            #pragma unroll
            for (int off = 1; off < 16; off <<= 1)
                pm = fminf(pm, __shfl_xor(pm, off, 64));
            if (lcol == 0)
                atomicMin(&rm[wn + i * 16 + lrow + r], __float_as_uint(pm));
        }
    }

    #pragma unroll
    for (int j = 0; j < 4; ++j) {
        float c = cmin[j];
        c = fminf(c, __shfl_xor(c, 16, 64));
        c = fminf(c, __shfl_xor(c, 32, 64));
        if ((lane >> 4) == 0)
            atomicMin(&cm[wm + j * 16 + lcol], __float_as_uint(c));
    }
}

// ---------------------------------------------------------------------------
// Finalize: out[b] = (sum(rowmin[b]) + sum(colmin[b])) / 1024
// ---------------------------------------------------------------------------
__global__ __launch_bounds__(256) void finalize_kernel(
        const unsigned int* __restrict__ rowmin,
        const unsigned int* __restrict__ colmin,
        float* __restrict__ out) {
    int b = blockIdx.x;
    int tid = threadIdx.x;
    float s = 0.0f;
    for (int i = tid; i < NN; i += 256) s += __uint_as_float(rowmin[b * NN + i]);
    for (int i = tid; i < MM; i += 256) s += __uint_as_float(colmin[b * MM + i]);
    #pragma unroll
    for (int off = 32; off; off >>= 1) s += __shfl_xor(s, off, 64);
    __shared__ float wsum[4];
    if ((tid & 63) == 0) wsum[tid >> 6] = s;
    __syncthreads();
    if (tid == 0) out[b] = (wsum[0] + wsum[1] + wsum[2] + wsum[3]) * (1.0f / 1024.0f);
}

// ---------------------------------------------------------------------------
extern "C" void kernel_launch(void* const* d_in, const int* in_sizes, int n_in,
                              void* d_out, int out_size, void* d_ws, size_t ws_size,
                              hipStream_t stream) {
    const float* h1 = (const float*)d_in[0];
    const float* h2 = (const float*)d_in[1];
    float* out = (float*)d_out;

    char* ws = (char*)d_ws;
    const size_t bf_bytes = (size_t)BB * NN * DD * sizeof(unsigned short); // 16 MB
    __hip_bfloat16* h1b = (__hip_bfloat16*)ws;
    __hip_bfloat16* h2b = (__hip_bfloat16*)(ws + bf_bytes);
    float* sq1 = (float*)(ws + 2 * bf_bytes);
    float* sq2 = sq1 + BB * NN;
    unsigned int* rowmin = (unsigned int*)(sq2 + BB * MM);
    unsigned int* colmin = rowmin + BB * NN;

    // 1) init min buffers: 2*BB*1024 = 65536 uints
    hipLaunchKernelGGL(init_minbuf, dim3(256), dim3(256), 0, stream, rowmin);

    // 2) convert + row norms: (BB*NN + BB*MM) rows, 4 waves/block
    hipLaunchKernelGGL(convert_kernel, dim3((BB * NN + BB * MM) / 4), dim3(256), 0, stream,
                       h1, h2, h1b, h2b, sq1, sq2);

    // 3) batched GEMM + fused min epilogue
    hipLaunchKernelGGL(gemm_kernel, dim3(64, BB), dim3(256), 0, stream,
                       h1b, h2b, sq1, sq2, rowmin, colmin);

    // 4) finalize
    hipLaunchKernelGGL(finalize_kernel, dim3(BB), dim3(256), 0, stream,
                       rowmin, colmin, out);
}